// Round 4
// baseline (153.662 us; speedup 1.0000x reference)
//
#include <hip/hip_runtime.h>
#include <hip/hip_bf16.h>

// CriticREM: out = relu(relu([state|action]W1^T+b1)W2^T+b2) @ Wc^T + bc
//   Wc = sum_h alpha_h * Wh[h], bc = sum_h alpha_h * bh[h]
// B=65536, IN=128, HID=256, NUM_HEADS=200, OUT=1
//
// R4: SPLIT into two high-occupancy streaming GEMMs, h1 via workspace (bf16,
//     33.5MB -> L3-resident between K1 and K2).
//   K1: zero __syncthreads (epilogue transpose via WAVE-PRIVATE LDS slice,
//       pitch 68 = 34 dw == 2 mod 32 -> conflict-free scatter), x A-frags
//       direct from global, W1 B-frags from L2 (64KB, hot).
//   K2: no staging LDS at all -- h1 A-frags are contiguous 16B global reads
//       (L3 hits); only the tiny final reduce barrier.
//   Both: launch_bounds(256,2) (84-116 VGPR, no spills), ~4 waves/SIMD.

#define B_TOTAL 65536
#define SDIM 96
#define ADIM 32
#define IN_F 128
#define HID 256
#define NHEADS 200
#define BM 64           // batch rows per block
#define TP 68           // K1 transpose-tile pitch (136B row = 34 dw == 2 mod 32)

typedef __bf16 bf16;
typedef __attribute__((ext_vector_type(8))) __bf16 bf16x8;
typedef __attribute__((ext_vector_type(4))) float f32x4;

// ---- prep: W1,W2 -> bf16 in ws; collapse heads: Wc[256], bc (fp32) ----
__global__ void prep_kernel(const float* __restrict__ W1, const float* __restrict__ W2,
                            const float* __restrict__ alphas, const float* __restrict__ Wh,
                            const float* __restrict__ bh,
                            bf16* __restrict__ W1bf, bf16* __restrict__ W2bf,
                            float* __restrict__ Wc) {
    int tid = blockIdx.x * blockDim.x + threadIdx.x;
    if (tid < IN_F * HID) W1bf[tid] = (bf16)W1[tid];
    if (tid < HID * HID)  W2bf[tid] = (bf16)W2[tid];
    if (tid < HID) {
        float acc = 0.f;
        #pragma unroll 8
        for (int h = 0; h < NHEADS; ++h) acc += alphas[h] * Wh[h * HID + tid];
        Wc[tid] = acc;
    }
    if (tid == HID) {
        float acc = 0.f;
        for (int h = 0; h < NHEADS; ++h) acc += alphas[h] * bh[h];
        Wc[HID] = acc;   // bc
    }
}

// ---- K1: h1[B,256] = relu(x @ W1^T + b1), bf16 row-major. NO barriers. ----
__global__ __launch_bounds__(256, 2) void gemm1_kernel(
        const float* __restrict__ state, const float* __restrict__ action,
        const float* __restrict__ b1, const bf16* __restrict__ W1bf,
        bf16* __restrict__ h1) {

    __shared__ bf16 tbuf[4][BM * TP];   // 4 x 8704 B = 34816 B, wave-private slices

    const int tid  = threadIdx.x;
    const int wave = tid >> 6;
    const int lane = tid & 63;
    const int q    = lane >> 4;
    const int ln   = lane & 15;
    const int colw = wave * 64;
    const int row0 = blockIdx.x * BM;

    f32x4 acc[4][4];
    #pragma unroll
    for (int mt = 0; mt < 4; ++mt)
        #pragma unroll
        for (int nt = 0; nt < 4; ++nt)
            acc[mt][nt] = (f32x4){0.f, 0.f, 0.f, 0.f};

    #pragma unroll
    for (int ks = 0; ks < 4; ++ks) {        // K = 128 = 4 x 32
        const int k0 = ks * 32 + q * 8;
        bf16x8 a[4], b[4];
        #pragma unroll
        for (int mt = 0; mt < 4; ++mt) {
            const size_t row = row0 + mt * 16 + ln;
            const float* src = (ks < 3) ? (state  + row * SDIM + k0)
                                        : (action + row * ADIM + q * 8);
            float4 v0 = ((const float4*)src)[0];
            float4 v1 = ((const float4*)src)[1];
            a[mt] = (bf16x8){(bf16)v0.x, (bf16)v0.y, (bf16)v0.z, (bf16)v0.w,
                             (bf16)v1.x, (bf16)v1.y, (bf16)v1.z, (bf16)v1.w};
        }
        #pragma unroll
        for (int nt = 0; nt < 4; ++nt)
            b[nt] = *(const bf16x8*)&W1bf[(size_t)(colw + nt * 16 + ln) * IN_F + k0];
        #pragma unroll
        for (int mt = 0; mt < 4; ++mt)
            #pragma unroll
            for (int nt = 0; nt < 4; ++nt)
                acc[mt][nt] = __builtin_amdgcn_mfma_f32_16x16x32_bf16(a[mt], b[nt], acc[mt][nt], 0, 0, 0);
    }

    // epilogue: bias+relu, scatter into WAVE-PRIVATE LDS tile (C-layout: col=ln, row=q*4+r)
    bf16* tl = tbuf[wave];
    #pragma unroll
    for (int nt = 0; nt < 4; ++nt) {
        const float bias = b1[colw + nt * 16 + ln];
        #pragma unroll
        for (int mt = 0; mt < 4; ++mt)
            #pragma unroll
            for (int r = 0; r < 4; ++r) {
                float v = acc[mt][nt][r] + bias;
                v = v > 0.f ? v : 0.f;
                tl[(mt * 16 + q * 4 + r) * TP + nt * 16 + ln] = (bf16)v;
            }
    }
    // same wave reads back row-major (compiler orders via lgkmcnt; no barrier needed)
    const int r8 = lane >> 3;   // 0..7
    const int c8 = lane & 7;    // 0..7
    #pragma unroll
    for (int i = 0; i < 8; ++i) {
        const int row = i * 8 + r8;
        bf16x8 v = *(const bf16x8*)&tl[row * TP + c8 * 8];
        *(bf16x8*)&h1[(size_t)(row0 + row) * HID + colw + c8 * 8] = v;
    }
}

// ---- K2: out = relu(h1 @ W2^T + b2) . Wc + bc. No staging LDS. ----
__global__ __launch_bounds__(256, 2) void gemm2_kernel(
        const bf16* __restrict__ h1, const float* __restrict__ b2,
        const bf16* __restrict__ W2bf, const float* __restrict__ Wc,
        float* __restrict__ out) {

    __shared__ float sPart[4][BM];

    const int tid  = threadIdx.x;
    const int wave = tid >> 6;
    const int lane = tid & 63;
    const int q    = lane >> 4;
    const int ln   = lane & 15;
    const int colw = wave * 64;
    const int row0 = blockIdx.x * BM;

    f32x4 acc[4][4];
    #pragma unroll
    for (int mt = 0; mt < 4; ++mt)
        #pragma unroll
        for (int nt = 0; nt < 4; ++nt)
            acc[mt][nt] = (f32x4){0.f, 0.f, 0.f, 0.f};

    #pragma unroll
    for (int ks = 0; ks < 8; ++ks) {        // K = 256 = 8 x 32
        const int k0 = ks * 32 + q * 8;
        bf16x8 a[4], b[4];
        #pragma unroll
        for (int mt = 0; mt < 4; ++mt)
            a[mt] = *(const bf16x8*)&h1[(size_t)(row0 + mt * 16 + ln) * HID + k0];
        #pragma unroll
        for (int nt = 0; nt < 4; ++nt)
            b[nt] = *(const bf16x8*)&W2bf[(size_t)(colw + nt * 16 + ln) * HID + k0];
        #pragma unroll
        for (int mt = 0; mt < 4; ++mt)
            #pragma unroll
            for (int nt = 0; nt < 4; ++nt)
                acc[mt][nt] = __builtin_amdgcn_mfma_f32_16x16x32_bf16(a[mt], b[nt], acc[mt][nt], 0, 0, 0);
    }

    // epilogue: bias + relu + dot with Wc, in-register; shfl-reduce over ln
    float partial[4][4];
    #pragma unroll
    for (int mt = 0; mt < 4; ++mt)
        #pragma unroll
        for (int r = 0; r < 4; ++r)
            partial[mt][r] = 0.f;

    #pragma unroll
    for (int nt = 0; nt < 4; ++nt) {
        const int n = colw + nt * 16 + ln;
        const float bias = b2[n];
        const float wc   = Wc[n];
        #pragma unroll
        for (int mt = 0; mt < 4; ++mt)
            #pragma unroll
            for (int r = 0; r < 4; ++r) {
                float v = acc[mt][nt][r] + bias;
                v = v > 0.f ? v : 0.f;
                partial[mt][r] += v * wc;
            }
    }

    #pragma unroll
    for (int off = 1; off < 16; off <<= 1)
        #pragma unroll
        for (int mt = 0; mt < 4; ++mt)
            #pragma unroll
            for (int r = 0; r < 4; ++r)
                partial[mt][r] += __shfl_xor(partial[mt][r], off, 64);

    if (ln == 0) {
        #pragma unroll
        for (int mt = 0; mt < 4; ++mt)
            #pragma unroll
            for (int r = 0; r < 4; ++r)
                sPart[wave][mt * 16 + q * 4 + r] = partial[mt][r];
    }
    __syncthreads();

    if (tid < BM) {
        float v = sPart[0][tid] + sPart[1][tid] + sPart[2][tid] + sPart[3][tid] + Wc[HID];
        out[row0 + tid] = v;
    }
}

extern "C" void kernel_launch(void* const* d_in, const int* in_sizes, int n_in,
                              void* d_out, int out_size, void* d_ws, size_t ws_size,
                              hipStream_t stream) {
    const float* state  = (const float*)d_in[0];
    const float* action = (const float*)d_in[1];
    const float* alphas = (const float*)d_in[2];
    const float* W1     = (const float*)d_in[3];
    const float* b1     = (const float*)d_in[4];
    const float* W2     = (const float*)d_in[5];
    const float* b2     = (const float*)d_in[6];
    const float* Wh     = (const float*)d_in[7];
    const float* bh     = (const float*)d_in[8];
    float* out = (float*)d_out;

    bf16*  W1bf = (bf16*)d_ws;                                   // @0,      65536 B
    bf16*  W2bf = (bf16*)((char*)d_ws + 65536);                  // @64K,   131072 B
    float* Wc   = (float*)((char*)d_ws + 65536 + 131072);        // @192K,    1028 B
    bf16*  h1   = (bf16*)((char*)d_ws + 262144);                 // @256K, 33554432 B

    prep_kernel<<<256, 256, 0, stream>>>(W1, W2, alphas, Wh, bh, W1bf, W2bf, Wc);
    gemm1_kernel<<<B_TOTAL / BM, 256, 0, stream>>>(state, action, b1, W1bf, h1);
    gemm2_kernel<<<B_TOTAL / BM, 256, 0, stream>>>(h1, b2, W2bf, Wc, out);
}

// Round 5
// 132.175 us; speedup vs baseline: 1.1626x; 1.1626x over previous
//
#include <hip/hip_runtime.h>
#include <hip/hip_bf16.h>

// CriticREM: out = relu(relu([state|action]W1^T+b1)W2^T+b2) @ Wc^T + bc
//   Wc = sum_h alpha_h * Wh[h], bc = sum_h alpha_h * bh[h]
// B=65536, IN=128, HID=256, NUM_HEADS=200, OUT=1
//
// R5: fused single kernel (R1 shape), latency-focused:
//   - W2 B-frags PREFETCHED into 128 VGPRs at kernel start -> GEMM2 has zero
//     global loads (prefetch drains behind GEMM1).
//   - GEMM1 A-frags direct from global (no xs stage): x + W1 loads issue as
//     one independent batch -> single exposed global-latency round per block.
//   - launch_bounds(256,2): 256-VGPR budget (no spills), 2 blocks/CU.
//   - one __syncthreads per block (h1 transpose); h1s pitch 260 == 0 conflicts
//     (measured R2).

#define B_TOTAL 65536
#define SDIM 96
#define ADIM 32
#define IN_F 128
#define HID 256
#define NHEADS 200
#define BM 64           // batch rows per block
#define H1_PITCH 260    // 520B row stride == 2 mod 32 dw: measured 0 conflicts

typedef __bf16 bf16;
typedef __attribute__((ext_vector_type(8))) __bf16 bf16x8;
typedef __attribute__((ext_vector_type(4))) float f32x4;

// ---- prep: W1,W2 -> bf16 in ws; collapse heads: Wc[256], bc (fp32) ----
__global__ void prep_kernel(const float* __restrict__ W1, const float* __restrict__ W2,
                            const float* __restrict__ alphas, const float* __restrict__ Wh,
                            const float* __restrict__ bh,
                            bf16* __restrict__ W1bf, bf16* __restrict__ W2bf,
                            float* __restrict__ Wc) {
    int tid = blockIdx.x * blockDim.x + threadIdx.x;
    if (tid < IN_F * HID) W1bf[tid] = (bf16)W1[tid];
    if (tid < HID * HID)  W2bf[tid] = (bf16)W2[tid];
    if (tid < HID) {
        float acc = 0.f;
        #pragma unroll 8
        for (int h = 0; h < NHEADS; ++h) acc += alphas[h] * Wh[h * HID + tid];
        Wc[tid] = acc;
    }
    if (tid == HID) {
        float acc = 0.f;
        for (int h = 0; h < NHEADS; ++h) acc += alphas[h] * bh[h];
        Wc[HID] = acc;   // bc
    }
}

// ---- main fused kernel: 256 threads (4 waves), 64 rows per block ----
__global__ __launch_bounds__(256, 2) void critic_kernel(
        const float* __restrict__ state, const float* __restrict__ action,
        const float* __restrict__ b1, const float* __restrict__ b2,
        const bf16* __restrict__ W1bf, const bf16* __restrict__ W2bf,
        const float* __restrict__ Wc, float* __restrict__ out) {

    __shared__ bf16 h1s[BM * H1_PITCH];    // 33280 B
    __shared__ float sPart[4][BM];         // 1024 B

    const int tid  = threadIdx.x;
    const int wave = tid >> 6;
    const int lane = tid & 63;
    const int q    = lane >> 4;     // 0..3
    const int ln   = lane & 15;     // 0..15
    const int colw = wave * 64;     // this wave's output-column slice
    const int row0 = blockIdx.x * BM;

    // ---- prefetch ALL W2 B-frags into registers (32 x bf16x8 = 128 VGPR) ----
    // These loads issue first; their vmcnt drains while GEMM1 runs.
    bf16x8 w2f[8][4];
    #pragma unroll
    for (int ks = 0; ks < 8; ++ks)
        #pragma unroll
        for (int nt = 0; nt < 4; ++nt)
            w2f[ks][nt] = *(const bf16x8*)&W2bf[(size_t)(colw + nt * 16 + ln) * HID + ks * 32 + q * 8];

    // per-lane epilogue constants (small scalar-ish loads, issue early too)
    float b1v[4], b2v[4], wcv[4];
    #pragma unroll
    for (int nt = 0; nt < 4; ++nt) {
        const int n = colw + nt * 16 + ln;
        b1v[nt] = b1[n];
        b2v[nt] = b2[n];
        wcv[nt] = Wc[n];
    }
    const float bc = Wc[HID];

    // ---- GEMM1: h1[64,256] = relu(x @ W1^T + b1) ----
    // A-frags direct from global: lane (q,ln) needs x[row=mt*16+ln][k0..k0+7].
    f32x4 acc[4][4];
    #pragma unroll
    for (int mt = 0; mt < 4; ++mt)
        #pragma unroll
        for (int nt = 0; nt < 4; ++nt)
            acc[mt][nt] = (f32x4){0.f, 0.f, 0.f, 0.f};

    #pragma unroll
    for (int ks = 0; ks < 4; ++ks) {        // K = 128 = 4 x 32
        const int k0 = ks * 32 + q * 8;
        bf16x8 a[4], b[4];
        #pragma unroll
        for (int mt = 0; mt < 4; ++mt) {
            const size_t row = row0 + mt * 16 + ln;
            const float* src = (ks < 3) ? (state  + row * SDIM + k0)
                                        : (action + row * ADIM + q * 8);
            float4 v0 = ((const float4*)src)[0];
            float4 v1 = ((const float4*)src)[1];
            a[mt] = (bf16x8){(bf16)v0.x, (bf16)v0.y, (bf16)v0.z, (bf16)v0.w,
                             (bf16)v1.x, (bf16)v1.y, (bf16)v1.z, (bf16)v1.w};
        }
        #pragma unroll
        for (int nt = 0; nt < 4; ++nt)
            b[nt] = *(const bf16x8*)&W1bf[(size_t)(colw + nt * 16 + ln) * IN_F + k0];
        #pragma unroll
        for (int mt = 0; mt < 4; ++mt)
            #pragma unroll
            for (int nt = 0; nt < 4; ++nt)
                acc[mt][nt] = __builtin_amdgcn_mfma_f32_16x16x32_bf16(a[mt], b[nt], acc[mt][nt], 0, 0, 0);
    }

    // epilogue 1: bias+relu -> h1s (C/D layout: col=ln, row=q*4+r)
    #pragma unroll
    for (int nt = 0; nt < 4; ++nt) {
        const int n = colw + nt * 16 + ln;
        #pragma unroll
        for (int mt = 0; mt < 4; ++mt)
            #pragma unroll
            for (int r = 0; r < 4; ++r) {
                float v = acc[mt][nt][r] + b1v[nt];
                v = v > 0.f ? v : 0.f;
                h1s[(mt * 16 + q * 4 + r) * H1_PITCH + n] = (bf16)v;
            }
    }
    __syncthreads();

    // ---- GEMM2: h2 = relu(h1 @ W2^T + b2) -- ZERO global loads here ----
    #pragma unroll
    for (int mt = 0; mt < 4; ++mt)
        #pragma unroll
        for (int nt = 0; nt < 4; ++nt)
            acc[mt][nt] = (f32x4){0.f, 0.f, 0.f, 0.f};

    #pragma unroll
    for (int ks = 0; ks < 8; ++ks) {        // K = 256 = 8 x 32
        const int k0 = ks * 32 + q * 8;
        bf16x8 a[4];
        #pragma unroll
        for (int mt = 0; mt < 4; ++mt)
            a[mt] = *(const bf16x8*)&h1s[(mt * 16 + ln) * H1_PITCH + k0];
        #pragma unroll
        for (int mt = 0; mt < 4; ++mt)
            #pragma unroll
            for (int nt = 0; nt < 4; ++nt)
                acc[mt][nt] = __builtin_amdgcn_mfma_f32_16x16x32_bf16(a[mt], w2f[ks][nt], acc[mt][nt], 0, 0, 0);
    }

    // epilogue 2: bias + relu + dot with Wc, in-register; shfl-reduce over ln
    float partial[4][4];
    #pragma unroll
    for (int mt = 0; mt < 4; ++mt)
        #pragma unroll
        for (int r = 0; r < 4; ++r)
            partial[mt][r] = 0.f;

    #pragma unroll
    for (int nt = 0; nt < 4; ++nt) {
        #pragma unroll
        for (int mt = 0; mt < 4; ++mt)
            #pragma unroll
            for (int r = 0; r < 4; ++r) {
                float v = acc[mt][nt][r] + b2v[nt];
                v = v > 0.f ? v : 0.f;
                partial[mt][r] += v * wcv[nt];
            }
    }

    #pragma unroll
    for (int off = 1; off < 16; off <<= 1)
        #pragma unroll
        for (int mt = 0; mt < 4; ++mt)
            #pragma unroll
            for (int r = 0; r < 4; ++r)
                partial[mt][r] += __shfl_xor(partial[mt][r], off, 64);

    if (ln == 0) {
        #pragma unroll
        for (int mt = 0; mt < 4; ++mt)
            #pragma unroll
            for (int r = 0; r < 4; ++r)
                sPart[wave][mt * 16 + q * 4 + r] = partial[mt][r];
    }
    __syncthreads();

    if (tid < BM) {
        float v = sPart[0][tid] + sPart[1][tid] + sPart[2][tid] + sPart[3][tid] + bc;
        out[row0 + tid] = v;
    }
}

extern "C" void kernel_launch(void* const* d_in, const int* in_sizes, int n_in,
                              void* d_out, int out_size, void* d_ws, size_t ws_size,
                              hipStream_t stream) {
    const float* state  = (const float*)d_in[0];
    const float* action = (const float*)d_in[1];
    const float* alphas = (const float*)d_in[2];
    const float* W1     = (const float*)d_in[3];
    const float* b1     = (const float*)d_in[4];
    const float* W2     = (const float*)d_in[5];
    const float* b2     = (const float*)d_in[6];
    const float* Wh     = (const float*)d_in[7];
    const float* bh     = (const float*)d_in[8];
    float* out = (float*)d_out;

    bf16*  W1bf = (bf16*)d_ws;                                  // 65536 B
    bf16*  W2bf = (bf16*)((char*)d_ws + 65536);                 // 131072 B
    float* Wc   = (float*)((char*)d_ws + 65536 + 131072);       // 257 * 4 B

    prep_kernel<<<256, 256, 0, stream>>>(W1, W2, alphas, Wh, bh, W1bf, W2bf, Wc);
    critic_kernel<<<B_TOTAL / BM, 256, 0, stream>>>(state, action, b1, b2, W1bf, W2bf, Wc, out);
}

// Round 6
// 114.884 us; speedup vs baseline: 1.3375x; 1.1505x over previous
//
#include <hip/hip_runtime.h>
#include <hip/hip_bf16.h>

// CriticREM: out = relu(relu([state|action]W1^T+b1)W2^T+b2) @ Wc^T + bc
//   Wc = sum_h alpha_h * Wh[h], bc = sum_h alpha_h * bh[h]
// B=65536, IN=128, HID=256, NUM_HEADS=200, OUT=1
//
// R6: persistent blocks + ALL weights register-resident + 2 waves/SIMD.
//   - 512-thread blocks (8 waves), each wave owns a 32-col slice:
//     w1f 32 VGPR + w2f 64 VGPR + acc 32 VGPR + px 16 ~= 184 VGPR < 256 cap
//     of launch_bounds(512,2) -> compiler keeps the prefetch (R5's (256,2)
//     cap made it sink the 128-VGPR w2f; VGPR_Count=104 proved it).
//   - grid=256 (1 block/CU), 4 tiles of 64 rows per block. Tile loop has ZERO
//     global loads except next-tile x prefetch (issued after barrier 1,
//     consumed one full tile later -> latency hidden behind MFMA).
//   - x staged through shared LDS (no per-wave duplication), pitch 132
//     (row stride 66 dw == 2 mod 32 -> conflict-free class, measured R2);
//     h1s pitch 260 (same class, measured 0 conflicts).

#define B_TOTAL 65536
#define SDIM 96
#define ADIM 32
#define IN_F 128
#define HID 256
#define NHEADS 200
#define BM 64           // batch rows per tile
#define NTILES 4        // tiles per block (grid 256)
#define XS_PITCH 132    // 264B row stride = 66 dw == 2 mod 32: conflict-free
#define H1_PITCH 260    // 520B row stride = 130 dw == 2 mod 32: measured 0

typedef __bf16 bf16;
typedef __attribute__((ext_vector_type(8))) __bf16 bf16x8;
typedef __attribute__((ext_vector_type(4))) float f32x4;

// ---- prep: W1,W2 -> bf16 in ws; collapse heads: Wc[256], bc (fp32) ----
__global__ void prep_kernel(const float* __restrict__ W1, const float* __restrict__ W2,
                            const float* __restrict__ alphas, const float* __restrict__ Wh,
                            const float* __restrict__ bh,
                            bf16* __restrict__ W1bf, bf16* __restrict__ W2bf,
                            float* __restrict__ Wc) {
    int tid = blockIdx.x * blockDim.x + threadIdx.x;
    if (tid < IN_F * HID) W1bf[tid] = (bf16)W1[tid];
    if (tid < HID * HID)  W2bf[tid] = (bf16)W2[tid];
    if (tid < HID) {
        float acc = 0.f;
        #pragma unroll 8
        for (int h = 0; h < NHEADS; ++h) acc += alphas[h] * Wh[h * HID + tid];
        Wc[tid] = acc;
    }
    if (tid == HID) {
        float acc = 0.f;
        for (int h = 0; h < NHEADS; ++h) acc += alphas[h] * bh[h];
        Wc[HID] = acc;   // bc
    }
}

// ---- main fused kernel: 512 threads (8 waves), persistent over 4 tiles ----
__global__ __launch_bounds__(512, 2) void critic_kernel(
        const float* __restrict__ state, const float* __restrict__ action,
        const float* __restrict__ b1, const float* __restrict__ b2,
        const bf16* __restrict__ W1bf, const bf16* __restrict__ W2bf,
        const float* __restrict__ Wc, float* __restrict__ out) {

    __shared__ bf16 xs[BM * XS_PITCH];     // 16896 B
    __shared__ bf16 h1s[BM * H1_PITCH];    // 33280 B
    __shared__ float sPart[8][BM];         // 2048 B   (~52 KB total)

    const int tid  = threadIdx.x;
    const int wave = tid >> 6;      // 0..7
    const int lane = tid & 63;
    const int q    = lane >> 4;     // 0..3
    const int ln   = lane & 15;     // 0..15
    const int colw = wave * 32;     // this wave's 32-col output slice
    const int brow0 = blockIdx.x * (BM * NTILES);

    // ---- preamble: ALL weight fragments into registers, once per block ----
    bf16x8 w1f[4][2];   // 32 VGPR
    #pragma unroll
    for (int ks = 0; ks < 4; ++ks)
        #pragma unroll
        for (int nt = 0; nt < 2; ++nt)
            w1f[ks][nt] = *(const bf16x8*)&W1bf[(size_t)(colw + nt * 16 + ln) * IN_F + ks * 32 + q * 8];

    bf16x8 w2f[8][2];   // 64 VGPR
    #pragma unroll
    for (int ks = 0; ks < 8; ++ks)
        #pragma unroll
        for (int nt = 0; nt < 2; ++nt)
            w2f[ks][nt] = *(const bf16x8*)&W2bf[(size_t)(colw + nt * 16 + ln) * HID + ks * 32 + q * 8];

    float b1v[2], b2v[2], wcv[2];
    #pragma unroll
    for (int nt = 0; nt < 2; ++nt) {
        const int n = colw + nt * 16 + ln;
        b1v[nt] = b1[n];
        b2v[nt] = b2[n];
        wcv[nt] = Wc[n];
    }
    const float bc = Wc[HID];

    // ---- x prefetch for tile 0: 512 threads x 2 chunks of 8 fp32 ----
    // chunk c = tid + i*512; r = c>>4 (16 chunks/row), c8 = c&15
    float4 px[2][2];
    #pragma unroll
    for (int i = 0; i < 2; ++i) {
        const int c  = tid + i * 512;
        const int r  = c >> 4;
        const int c8 = c & 15;
        const float* src = (c8 < 12) ? (state  + (size_t)(brow0 + r) * SDIM + c8 * 8)
                                     : (action + (size_t)(brow0 + r) * ADIM + (c8 - 12) * 8);
        px[i][0] = ((const float4*)src)[0];
        px[i][1] = ((const float4*)src)[1];
    }

    for (int t = 0; t < NTILES; ++t) {
        const int row0 = brow0 + t * BM;

        // stage x tile: convert prefetched fp32 -> bf16, write LDS
        #pragma unroll
        for (int i = 0; i < 2; ++i) {
            const int c  = tid + i * 512;
            const int r  = c >> 4;
            const int c8 = c & 15;
            bf16x8 v = (bf16x8){(bf16)px[i][0].x, (bf16)px[i][0].y, (bf16)px[i][0].z, (bf16)px[i][0].w,
                                (bf16)px[i][1].x, (bf16)px[i][1].y, (bf16)px[i][1].z, (bf16)px[i][1].w};
            *(bf16x8*)&xs[r * XS_PITCH + c8 * 8] = v;
        }
        __syncthreads();

        // prefetch NEXT tile's x while this tile's MFMAs run
        if (t + 1 < NTILES) {
            const int nrow0 = row0 + BM;
            #pragma unroll
            for (int i = 0; i < 2; ++i) {
                const int c  = tid + i * 512;
                const int r  = c >> 4;
                const int c8 = c & 15;
                const float* src = (c8 < 12) ? (state  + (size_t)(nrow0 + r) * SDIM + c8 * 8)
                                             : (action + (size_t)(nrow0 + r) * ADIM + (c8 - 12) * 8);
                px[i][0] = ((const float4*)src)[0];
                px[i][1] = ((const float4*)src)[1];
            }
        }

        // ---- GEMM1: h1 = relu(x @ W1^T + b1), wave cols [colw, colw+32) ----
        f32x4 acc[4][2];
        #pragma unroll
        for (int mt = 0; mt < 4; ++mt)
            #pragma unroll
            for (int nt = 0; nt < 2; ++nt)
                acc[mt][nt] = (f32x4){0.f, 0.f, 0.f, 0.f};

        #pragma unroll
        for (int ks = 0; ks < 4; ++ks) {
            const int k0 = ks * 32 + q * 8;
            bf16x8 a[4];
            #pragma unroll
            for (int mt = 0; mt < 4; ++mt)
                a[mt] = *(const bf16x8*)&xs[(mt * 16 + ln) * XS_PITCH + k0];
            #pragma unroll
            for (int mt = 0; mt < 4; ++mt)
                #pragma unroll
                for (int nt = 0; nt < 2; ++nt)
                    acc[mt][nt] = __builtin_amdgcn_mfma_f32_16x16x32_bf16(a[mt], w1f[ks][nt], acc[mt][nt], 0, 0, 0);
        }

        // epilogue 1: bias+relu -> h1s (C/D layout: col=ln, row=q*4+r)
        #pragma unroll
        for (int nt = 0; nt < 2; ++nt) {
            const int n = colw + nt * 16 + ln;
            #pragma unroll
            for (int mt = 0; mt < 4; ++mt)
                #pragma unroll
                for (int r = 0; r < 4; ++r) {
                    float v = acc[mt][nt][r] + b1v[nt];
                    v = v > 0.f ? v : 0.f;
                    h1s[(mt * 16 + q * 4 + r) * H1_PITCH + n] = (bf16)v;
                }
        }
        __syncthreads();

        // ---- GEMM2: h2 = relu(h1 @ W2^T + b2) -- zero global loads ----
        #pragma unroll
        for (int mt = 0; mt < 4; ++mt)
            #pragma unroll
            for (int nt = 0; nt < 2; ++nt)
                acc[mt][nt] = (f32x4){0.f, 0.f, 0.f, 0.f};

        #pragma unroll
        for (int ks = 0; ks < 8; ++ks) {
            const int k0 = ks * 32 + q * 8;
            bf16x8 a[4];
            #pragma unroll
            for (int mt = 0; mt < 4; ++mt)
                a[mt] = *(const bf16x8*)&h1s[(mt * 16 + ln) * H1_PITCH + k0];
            #pragma unroll
            for (int mt = 0; mt < 4; ++mt)
                #pragma unroll
                for (int nt = 0; nt < 2; ++nt)
                    acc[mt][nt] = __builtin_amdgcn_mfma_f32_16x16x32_bf16(a[mt], w2f[ks][nt], acc[mt][nt], 0, 0, 0);
        }

        // epilogue 2: bias+relu, dot with Wc, shfl-reduce over ln
        float partial[4][4];
        #pragma unroll
        for (int mt = 0; mt < 4; ++mt)
            #pragma unroll
            for (int r = 0; r < 4; ++r)
                partial[mt][r] = 0.f;

        #pragma unroll
        for (int nt = 0; nt < 2; ++nt) {
            #pragma unroll
            for (int mt = 0; mt < 4; ++mt)
                #pragma unroll
                for (int r = 0; r < 4; ++r) {
                    float v = acc[mt][nt][r] + b2v[nt];
                    v = v > 0.f ? v : 0.f;
                    partial[mt][r] += v * wcv[nt];
                }
        }

        #pragma unroll
        for (int off = 1; off < 16; off <<= 1)
            #pragma unroll
            for (int mt = 0; mt < 4; ++mt)
                #pragma unroll
                for (int r = 0; r < 4; ++r)
                    partial[mt][r] += __shfl_xor(partial[mt][r], off, 64);

        if (ln == 0) {
            #pragma unroll
            for (int mt = 0; mt < 4; ++mt)
                #pragma unroll
                for (int r = 0; r < 4; ++r)
                    sPart[wave][mt * 16 + q * 4 + r] = partial[mt][r];
        }
        __syncthreads();

        if (tid < BM) {
            float v = bc;
            #pragma unroll
            for (int w = 0; w < 8; ++w) v += sPart[w][tid];
            out[row0 + tid] = v;
        }
        // end-of-tile barrier is the sPart one above: next tile's xs writes
        // are ordered after all of this tile's xs/h1s reads.
    }
}

extern "C" void kernel_launch(void* const* d_in, const int* in_sizes, int n_in,
                              void* d_out, int out_size, void* d_ws, size_t ws_size,
                              hipStream_t stream) {
    const float* state  = (const float*)d_in[0];
    const float* action = (const float*)d_in[1];
    const float* alphas = (const float*)d_in[2];
    const float* W1     = (const float*)d_in[3];
    const float* b1     = (const float*)d_in[4];
    const float* W2     = (const float*)d_in[5];
    const float* b2     = (const float*)d_in[6];
    const float* Wh     = (const float*)d_in[7];
    const float* bh     = (const float*)d_in[8];
    float* out = (float*)d_out;

    bf16*  W1bf = (bf16*)d_ws;                                  // 65536 B
    bf16*  W2bf = (bf16*)((char*)d_ws + 65536);                 // 131072 B
    float* Wc   = (float*)((char*)d_ws + 65536 + 131072);       // 257 * 4 B

    prep_kernel<<<256, 256, 0, stream>>>(W1, W2, alphas, Wh, bh, W1bf, W2bf, Wc);
    critic_kernel<<<B_TOTAL / (BM * NTILES), 512, 0, stream>>>(state, action, b1, b2, W1bf, W2bf, Wc, out);
}

// Round 7
// 111.145 us; speedup vs baseline: 1.3825x; 1.0336x over previous
//
#include <hip/hip_runtime.h>
#include <hip/hip_bf16.h>

// CriticREM: out = relu(relu([state|action]W1^T+b1)W2^T+b2) @ Wc^T + bc
//   Wc = sum_h alpha_h * Wh[h], bc = sum_h alpha_h * bh[h]
// B=65536, IN=128, HID=256, NUM_HEADS=200, OUT=1
//
// R7: R6 persistent structure + TRANSPOSED GEMMs to slash LDS-pipe work.
//   Both GEMMs compute D[n][m] = W * x^T (weights as the A operand, activations
//   as B). A/B frag layouts are symmetric, so the same register-resident weight
//   frags and the same contiguous LDS row reads are reused. C-layout flips:
//   col=ln -> batch row, row=q*4+r -> hidden col. Wins:
//     - epi1: 4 regs = 4 consecutive hidden cols at one batch row ->
//       ds_write_b64 x8 per lane (was 32x ds_write_b16).
//     - epi2: Wc-dot over hidden is IN-LANE; cross-lane reduce only over q:
//       2 shfl steps x 4 vals (was 4 steps x 16 vals, ds-swizzle pipe).
//     - bias/Wc epilogue constants load as contiguous float4.
//   LDS instrs/tile ~1300 -> ~570 (the measured-R6 bottleneck).

#define B_TOTAL 65536
#define SDIM 96
#define ADIM 32
#define IN_F 128
#define HID 256
#define NHEADS 200
#define BM 64           // batch rows per tile
#define NTILES 4        // tiles per block (grid 256)
#define XS_PITCH 132    // 264B row stride = 66 dw == 2 mod 32: conflict-free class
#define H1_PITCH 260    // 520B row stride = 130 dw == 2 mod 32: measured 0 (R2)

typedef __bf16 bf16;
typedef __attribute__((ext_vector_type(4))) __bf16 bf16x4;
typedef __attribute__((ext_vector_type(8))) __bf16 bf16x8;
typedef __attribute__((ext_vector_type(4))) float f32x4;

// ---- prep: W1,W2 -> bf16 in ws; collapse heads: Wc[256], bc (fp32) ----
__global__ void prep_kernel(const float* __restrict__ W1, const float* __restrict__ W2,
                            const float* __restrict__ alphas, const float* __restrict__ Wh,
                            const float* __restrict__ bh,
                            bf16* __restrict__ W1bf, bf16* __restrict__ W2bf,
                            float* __restrict__ Wc) {
    int tid = blockIdx.x * blockDim.x + threadIdx.x;
    if (tid < IN_F * HID) W1bf[tid] = (bf16)W1[tid];
    if (tid < HID * HID)  W2bf[tid] = (bf16)W2[tid];
    if (tid < HID) {
        float acc = 0.f;
        #pragma unroll 8
        for (int h = 0; h < NHEADS; ++h) acc += alphas[h] * Wh[h * HID + tid];
        Wc[tid] = acc;
    }
    if (tid == HID) {
        float acc = 0.f;
        for (int h = 0; h < NHEADS; ++h) acc += alphas[h] * bh[h];
        Wc[HID] = acc;   // bc
    }
}

// ---- main fused kernel: 512 threads (8 waves), persistent over 4 tiles ----
__global__ __launch_bounds__(512, 2) void critic_kernel(
        const float* __restrict__ state, const float* __restrict__ action,
        const float* __restrict__ b1, const float* __restrict__ b2,
        const bf16* __restrict__ W1bf, const bf16* __restrict__ W2bf,
        const float* __restrict__ Wc, float* __restrict__ out) {

    __shared__ bf16 xs[BM * XS_PITCH];     // 16896 B, x tile [batch][k]
    __shared__ bf16 h1s[BM * H1_PITCH];    // 33280 B, h1 tile [batch][hidden]
    __shared__ float sPart[8][BM];         // 2048 B

    const int tid  = threadIdx.x;
    const int wave = tid >> 6;      // 0..7
    const int lane = tid & 63;
    const int q    = lane >> 4;     // 0..3
    const int ln   = lane & 15;     // 0..15
    const int colw = wave * 32;     // this wave's 32-hidden-col slice
    const int brow0 = blockIdx.x * (BM * NTILES);

    // ---- preamble: ALL weight fragments into registers, once per block ----
    // A-operand layout: A[m'=ln][k=q*8+j] -> same data we always loaded.
    bf16x8 w1f[4][2];   // 32 VGPR : W1[colw+nt*16+ln][ks*32+q*8 ..]
    #pragma unroll
    for (int ks = 0; ks < 4; ++ks)
        #pragma unroll
        for (int nt = 0; nt < 2; ++nt)
            w1f[ks][nt] = *(const bf16x8*)&W1bf[(size_t)(colw + nt * 16 + ln) * IN_F + ks * 32 + q * 8];

    bf16x8 w2f[8][2];   // 64 VGPR
    #pragma unroll
    for (int ks = 0; ks < 8; ++ks)
        #pragma unroll
        for (int nt = 0; nt < 2; ++nt)
            w2f[ks][nt] = *(const bf16x8*)&W2bf[(size_t)(colw + nt * 16 + ln) * HID + ks * 32 + q * 8];

    // epilogue constants: hidden col n = colw + nt*16 + q*4 + r  -> float4 loads
    f32x4 b1v[2], b2v[2], wcv[2];
    #pragma unroll
    for (int nt = 0; nt < 2; ++nt) {
        const int n4 = colw + nt * 16 + q * 4;
        b1v[nt] = *(const f32x4*)&b1[n4];
        b2v[nt] = *(const f32x4*)&b2[n4];
        wcv[nt] = *(const f32x4*)&Wc[n4];
    }
    const float bc = Wc[HID];

    // ---- x prefetch for tile 0: 512 threads x 2 chunks of 8 fp32 ----
    float4 px[2][2];
    #pragma unroll
    for (int i = 0; i < 2; ++i) {
        const int c  = tid + i * 512;
        const int r  = c >> 4;
        const int c8 = c & 15;
        const float* src = (c8 < 12) ? (state  + (size_t)(brow0 + r) * SDIM + c8 * 8)
                                     : (action + (size_t)(brow0 + r) * ADIM + (c8 - 12) * 8);
        px[i][0] = ((const float4*)src)[0];
        px[i][1] = ((const float4*)src)[1];
    }

    for (int t = 0; t < NTILES; ++t) {
        const int row0 = brow0 + t * BM;

        // stage x tile: fp32 -> bf16 into LDS [batch][k]
        #pragma unroll
        for (int i = 0; i < 2; ++i) {
            const int c  = tid + i * 512;
            const int r  = c >> 4;
            const int c8 = c & 15;
            bf16x8 v = (bf16x8){(bf16)px[i][0].x, (bf16)px[i][0].y, (bf16)px[i][0].z, (bf16)px[i][0].w,
                                (bf16)px[i][1].x, (bf16)px[i][1].y, (bf16)px[i][1].z, (bf16)px[i][1].w};
            *(bf16x8*)&xs[r * XS_PITCH + c8 * 8] = v;
        }
        __syncthreads();

        // prefetch NEXT tile's x while this tile computes
        if (t + 1 < NTILES) {
            const int nrow0 = row0 + BM;
            #pragma unroll
            for (int i = 0; i < 2; ++i) {
                const int c  = tid + i * 512;
                const int r  = c >> 4;
                const int c8 = c & 15;
                const float* src = (c8 < 12) ? (state  + (size_t)(nrow0 + r) * SDIM + c8 * 8)
                                             : (action + (size_t)(nrow0 + r) * ADIM + (c8 - 12) * 8);
                px[i][0] = ((const float4*)src)[0];
                px[i][1] = ((const float4*)src)[1];
            }
        }

        // ---- GEMM1 (transposed): D1[n][m] = W1 . x^T over this wave's 32 n ----
        // A = w1f (regs), B = xs rows: B[k=q*8+j][m'=ln] = x[mt*16+ln][ks*32+q*8+j]
        f32x4 acc[4][2];   // [mt][nt]
        #pragma unroll
        for (int mt = 0; mt < 4; ++mt)
            #pragma unroll
            for (int nt = 0; nt < 2; ++nt)
                acc[mt][nt] = (f32x4){0.f, 0.f, 0.f, 0.f};

        #pragma unroll
        for (int ks = 0; ks < 4; ++ks) {
            const int k0 = ks * 32 + q * 8;
            bf16x8 bfr[4];
            #pragma unroll
            for (int mt = 0; mt < 4; ++mt)
                bfr[mt] = *(const bf16x8*)&xs[(mt * 16 + ln) * XS_PITCH + k0];
            #pragma unroll
            for (int mt = 0; mt < 4; ++mt)
                #pragma unroll
                for (int nt = 0; nt < 2; ++nt)
                    acc[mt][nt] = __builtin_amdgcn_mfma_f32_16x16x32_bf16(w1f[ks][nt], bfr[mt], acc[mt][nt], 0, 0, 0);
        }

        // epi1: bias+relu; regs r=0..3 are 4 CONSECUTIVE hidden cols at batch
        // row mt*16+ln -> one ds_write_b64 per (nt,mt)
        #pragma unroll
        for (int nt = 0; nt < 2; ++nt) {
            #pragma unroll
            for (int mt = 0; mt < 4; ++mt) {
                bf16x4 v4;
                #pragma unroll
                for (int r = 0; r < 4; ++r) {
                    float v = acc[mt][nt][r] + b1v[nt][r];
                    v = v > 0.f ? v : 0.f;
                    v4[r] = (bf16)v;
                }
                *(bf16x4*)&h1s[(mt * 16 + ln) * H1_PITCH + colw + nt * 16 + q * 4] = v4;
            }
        }
        __syncthreads();

        // ---- GEMM2 (transposed): D2[n][m] = W2 . h1^T ----
        #pragma unroll
        for (int mt = 0; mt < 4; ++mt)
            #pragma unroll
            for (int nt = 0; nt < 2; ++nt)
                acc[mt][nt] = (f32x4){0.f, 0.f, 0.f, 0.f};

        #pragma unroll
        for (int ks = 0; ks < 8; ++ks) {
            const int k0 = ks * 32 + q * 8;
            bf16x8 bfr[4];
            #pragma unroll
            for (int mt = 0; mt < 4; ++mt)
                bfr[mt] = *(const bf16x8*)&h1s[(mt * 16 + ln) * H1_PITCH + k0];
            #pragma unroll
            for (int mt = 0; mt < 4; ++mt)
                #pragma unroll
                for (int nt = 0; nt < 2; ++nt)
                    acc[mt][nt] = __builtin_amdgcn_mfma_f32_16x16x32_bf16(w2f[ks][nt], bfr[mt], acc[mt][nt], 0, 0, 0);
        }

        // epi2: bias+relu+Wc-dot IN-LANE over (nt,r); per-lane partial[mt] is
        // the contribution of hidden cols {colw+nt*16+q*4+r} to batch row
        // mt*16+ln. Cross-lane reduce only over q: shfl_xor 16,32.
        float partial[4];
        #pragma unroll
        for (int mt = 0; mt < 4; ++mt) {
            float p = 0.f;
            #pragma unroll
            for (int nt = 0; nt < 2; ++nt)
                #pragma unroll
                for (int r = 0; r < 4; ++r) {
                    float v = acc[mt][nt][r] + b2v[nt][r];
                    v = v > 0.f ? v : 0.f;
                    p += v * wcv[nt][r];
                }
            partial[mt] = p;
        }
        #pragma unroll
        for (int mt = 0; mt < 4; ++mt) {
            partial[mt] += __shfl_xor(partial[mt], 16, 64);
            partial[mt] += __shfl_xor(partial[mt], 32, 64);
        }
        if (q == 0) {
            #pragma unroll
            for (int mt = 0; mt < 4; ++mt)
                sPart[wave][mt * 16 + ln] = partial[mt];
        }
        __syncthreads();

        if (tid < BM) {
            float v = bc;
            #pragma unroll
            for (int w = 0; w < 8; ++w) v += sPart[w][tid];
            out[row0 + tid] = v;
        }
        // barrier above also orders next tile's xs writes after this tile's reads
    }
}

extern "C" void kernel_launch(void* const* d_in, const int* in_sizes, int n_in,
                              void* d_out, int out_size, void* d_ws, size_t ws_size,
                              hipStream_t stream) {
    const float* state  = (const float*)d_in[0];
    const float* action = (const float*)d_in[1];
    const float* alphas = (const float*)d_in[2];
    const float* W1     = (const float*)d_in[3];
    const float* b1     = (const float*)d_in[4];
    const float* W2     = (const float*)d_in[5];
    const float* b2     = (const float*)d_in[6];
    const float* Wh     = (const float*)d_in[7];
    const float* bh     = (const float*)d_in[8];
    float* out = (float*)d_out;

    bf16*  W1bf = (bf16*)d_ws;                                  // 65536 B
    bf16*  W2bf = (bf16*)((char*)d_ws + 65536);                 // 131072 B
    float* Wc   = (float*)((char*)d_ws + 65536 + 131072);       // 257 * 4 B

    prep_kernel<<<256, 256, 0, stream>>>(W1, W2, alphas, Wh, bh, W1bf, W2bf, Wc);
    critic_kernel<<<B_TOTAL / (BM * NTILES), 512, 0, stream>>>(state, action, b1, b2, W1bf, W2bf, Wc, out);
}